// Round 17
// baseline (138.372 us; speedup 1.0000x reference)
//
#include <hip/hip_runtime.h>
#include <math.h>
#include <stdint.h>

#define BB  16
#define IDF 128
#define CDF 256
#define SL  48
#define QQ  16384   // 128*128
#define QT  64      // q-tile per block

typedef short bf16x8 __attribute__((ext_vector_type(8)));
typedef short bf16x4 __attribute__((ext_vector_type(4)));
typedef float f32x4  __attribute__((ext_vector_type(4)));

__device__ __forceinline__ short f2bf(float f) {      // RNE
    uint32_t u = __builtin_bit_cast(uint32_t, f);
    u += 0x7FFFu + ((u >> 16) & 1u);
    return (short)(u >> 16);
}
__device__ __forceinline__ short f2bf_t(float f) {    // truncate (for lo terms)
    return (short)(__builtin_bit_cast(uint32_t, f) >> 16);
}
__device__ __forceinline__ float bf2f(short h) {
    uint32_t u = ((uint32_t)(unsigned short)h) << 16;
    return __builtin_bit_cast(float, u);
}

// Barrier that orders LDS only (lgkmcnt) and lets global NT stores stay in
// flight (r16: -6 µs vs full __syncthreads drains).
__device__ __forceinline__ void bar_lds() {
    __builtin_amdgcn_sched_barrier(0);
    asm volatile("s_waitcnt lgkmcnt(0)" ::: "memory");
    __builtin_amdgcn_s_barrier();
    __builtin_amdgcn_sched_barrier(0);
}

// ============ prepM: srcT via MFMA + direct frag-array emission ============
__global__ __launch_bounds__(256) void prepM_kernel(
    const float* __restrict__ context,   // [B][CDF][SL]
    const float* __restrict__ w_ctx,     // [IDF][CDF]
    const float* __restrict__ sentence,  // [B][100]
    const float* __restrict__ w_lin,     // [IDF][100]
    const float* __restrict__ b_lin,     // [IDF]
    const float* __restrict__ w_sv,      // [IDF o][IDF i]
    const int*   __restrict__ mask,      // [B][SL]
    float* __restrict__ sentW,           // [B][IDF]
    float* __restrict__ biasB,           // [B][SL]
    short* __restrict__ wsvS,            // [B][8Mt][4ks][64][8]
    short* __restrict__ stB,             // [B][3Mt][4ks][2][64][8]
    short* __restrict__ stC)             // [B][8Mt][2ks][64][8]
{
    const int b = blockIdx.x;
    const int t = threadIdx.x;
    const int wv = t >> 6, l = t & 63;
    const int c = l & 15, g = l >> 4;

    __shared__ __align__(16) short ctxT_h[SL * CDF];   // 24 KB [s][c^swz] hi
    __shared__ __align__(16) short ctxT_l[SL * CDF];   // 24 KB lo
    __shared__ float srcTile[IDF * SL];                // 24 KB [i][s]
    __shared__ float sent_sh[IDF];

    if (t < IDF) {
        float a = b_lin[t];
        for (int k = 0; k < 100; ++k)
            a += sentence[b * 100 + k] * w_lin[t * 100 + k];
        sent_sh[t] = a;
        sentW[b * IDF + t] = a;
    }
    if (t >= IDF && t < IDF + SL) {
        int s = t - IDF;
        biasB[b * SL + s] = mask[b * SL + s] ? -INFINITY : 0.f;
    }

    for (int r = 0; r < 6; ++r) {
        int task = r * 256 + t;
        int cp = task & 127, s4 = task >> 7;
        int cd = cp * 2, sb = s4 * 4;
        const float* row0 = context + ((size_t)b * CDF + cd) * SL + sb;
        const float4 va = *(const float4*)(row0);
        const float4 vb = *(const float4*)(row0 + SL);
        float va_[4] = {va.x, va.y, va.z, va.w};
        float vb_[4] = {vb.x, vb.y, vb.z, vb.w};
        #pragma unroll
        for (int j = 0; j < 4; ++j) {
            int s = sb + j;
            short h0 = f2bf(va_[j]), h1 = f2bf(vb_[j]);
            short l0 = f2bf_t(va_[j] - bf2f(h0)), l1 = f2bf_t(vb_[j] - bf2f(h1));
            int e = s * CDF + (cd ^ ((s & 15) << 3));
            *(uint32_t*)(ctxT_h + e) = (uint32_t)(uint16_t)h0 | ((uint32_t)(uint16_t)h1 << 16);
            *(uint32_t*)(ctxT_l + e) = (uint32_t)(uint16_t)l0 | ((uint32_t)(uint16_t)l1 << 16);
        }
    }
    __syncthreads();

    #pragma unroll
    for (int mi = 0; mi < 2; ++mi) {
        const int Mt = wv * 2 + mi;
        const int m = 16 * Mt + c;
        bf16x8 Ah[8], Al[8];
        #pragma unroll
        for (int ks = 0; ks < 8; ++ks) {
            const float* wp = w_ctx + m * CDF + 8 * g + 32 * ks;
            const float4 f0 = *(const float4*)(wp);
            const float4 f1 = *(const float4*)(wp + 4);
            float fv[8] = {f0.x, f0.y, f0.z, f0.w, f1.x, f1.y, f1.z, f1.w};
            #pragma unroll
            for (int j = 0; j < 8; ++j) {
                short h = f2bf(fv[j]);
                Ah[ks][j] = h;
                Al[ks][j] = f2bf_t(fv[j] - bf2f(h));
            }
        }
        #pragma unroll
        for (int Nt = 0; Nt < 3; ++Nt) {
            const int s = 16 * Nt + c;
            f32x4 acc = {0.f, 0.f, 0.f, 0.f};
            #pragma unroll
            for (int ks = 0; ks < 8; ++ks) {
                int e = s * CDF + ((8 * g + 32 * ks) ^ ((s & 15) << 3));
                const bf16x8 Bh = *(const bf16x8*)(ctxT_h + e);
                const bf16x8 Bl = *(const bf16x8*)(ctxT_l + e);
                acc = __builtin_amdgcn_mfma_f32_16x16x32_bf16(Ah[ks], Bh, acc, 0, 0, 0);
                acc = __builtin_amdgcn_mfma_f32_16x16x32_bf16(Ah[ks], Bl, acc, 0, 0, 0);
                acc = __builtin_amdgcn_mfma_f32_16x16x32_bf16(Al[ks], Bh, acc, 0, 0, 0);
            }
            #pragma unroll
            for (int r = 0; r < 4; ++r)
                srcTile[(16 * Mt + 4 * g + r) * SL + s] = acc[r];
        }
    }
    __syncthreads();

    #pragma unroll
    for (int cc = 0; cc < 3; ++cc) {
        int comb = wv * 3 + cc;
        int Mt = comb >> 2, ks = comb & 3;
        int s = c + 16 * Mt;
        int ib = 8 * g + 32 * ks;
        bf16x8 hv, lv;
        #pragma unroll
        for (int j = 0; j < 8; ++j) {
            float v = srcTile[(ib + j) * SL + s];
            short h = f2bf(v);
            hv[j] = h;
            lv[j] = f2bf_t(v - bf2f(h));
        }
        size_t base = (size_t)b * 12288 + (((Mt * 4 + ks) * 2) * 64 + l) * 8;
        *(bf16x8*)(stB + base) = hv;
        *(bf16x8*)(stB + base + 512) = lv;
    }
    #pragma unroll
    for (int cc = 0; cc < 4; ++cc) {
        int comb = wv * 4 + cc;
        int Mt = comb >> 1, ks = comb & 1;
        int i = c + 16 * Mt;
        int sb = 8 * g + 32 * ks;
        bf16x8 v8;
        #pragma unroll
        for (int j = 0; j < 8; ++j) {
            int s = sb + j;
            v8[j] = (s < SL) ? f2bf(srcTile[i * SL + s]) : (short)0;
        }
        *(bf16x8*)(stC + (size_t)b * 8192 + ((Mt * 2 + ks) * 64 + l) * 8) = v8;
    }
    #pragma unroll
    for (int cc = 0; cc < 8; ++cc) {
        int comb = wv * 8 + cc;
        int Mt = comb >> 2, ks = comb & 3;
        int o = c + 16 * Mt;
        int ib = g * 8 + 32 * ks;
        bf16x8 outv;
        #pragma unroll
        for (int j = 0; j < 8; ++j)
            outv[j] = f2bf(w_sv[o * IDF + ib + j] * sent_sh[ib + j]);
        *(bf16x8*)(wsvS + (size_t)b * 16384 + ((Mt * 4 + ks) * 64 + l) * 8) = outv;
    }
}

// ===================== fused MFMA kernel =====================
// r16 structure + NT input loads: `input` is streamed once and never
// reused — NT loads keep it from sweeping L2, preserving residency for the
// frag arrays (72 KB/b, re-read by all 256 blocks of that b).
__global__ __launch_bounds__(256, 4) void fused_kernel(
    const float* __restrict__ input,   // [B][IDF][Q]
    const short* __restrict__ stB,
    const short* __restrict__ stC,
    const short* __restrict__ wsvS,
    const float* __restrict__ sentW,   // [B][IDF]
    const float* __restrict__ biasB,   // [B][SL]
    float* __restrict__ wctx, float* __restrict__ wsent,
    float* __restrict__ wattn, float* __restrict__ satt)
{
    const int bid = blockIdx.x;           // 4096 = 16 b x 256 tiles
    const int b   = bid >> 8;
    const int q0  = (bid & 255) * QT;
    const int t   = threadIdx.x;
    const int w   = t >> 6;               // wave -> q-strip (16 q)
    const int l   = t & 63;
    const int c   = l & 15;
    const int g   = l >> 4;

    __shared__ __align__(16) short xq[2 * QT * IDF];  // 32768 B

    short* xqh = xq;                      // 16 KB
    short* xql = xq + QT * IDF;           // 16 KB

    // ---- stage x transposed, hi/lo split (NT loads: stream-once data) ----
    {
        const int qb = (t & 15) * 4;
        #pragma unroll
        for (int r = 0; r < 4; ++r) {
            int i = (r * 16 + (t >> 4)) * 2;
            const f32x4 va = __builtin_nontemporal_load(
                (const f32x4*)(input + ((size_t)b * IDF + i    ) * QQ + q0 + qb));
            const f32x4 vb = __builtin_nontemporal_load(
                (const f32x4*)(input + ((size_t)b * IDF + i + 1) * QQ + q0 + qb));
            #pragma unroll
            for (int jj = 0; jj < 4; ++jj) {
                int q = qb + jj;
                short h0 = f2bf(va[jj]);
                short h1 = f2bf(vb[jj]);
                short l0 = f2bf_t(va[jj] - bf2f(h0));
                short l1 = f2bf_t(vb[jj] - bf2f(h1));
                int e = q * IDF + (i ^ ((q & 15) << 3));   // i even -> e even
                *(uint32_t*)(xqh + e) = (uint32_t)(uint16_t)h0 | ((uint32_t)(uint16_t)h1 << 16);
                *(uint32_t*)(xql + e) = (uint32_t)(uint16_t)l0 | ((uint32_t)(uint16_t)l1 << 16);
            }
        }
    }
    bar_lds();                                        // bar1

    // ---- x B-fragments: plain b128, k = 32*ks + 8*g + j, n(q-col) = c ----
    const int qrow = 16 * w + c;
    const short* xh_p = xqh + qrow * IDF;
    const short* xl_p = xql + qrow * IDF;
    bf16x8 fxh[4], fxl[4];
    #pragma unroll
    for (int ks = 0; ks < 4; ++ks) {
        int off = (32 * ks + 8 * g) ^ (c << 3);       // qrow&15 == c
        fxh[ks] = *(const bf16x8*)(xh_p + off);
        fxl[ks] = *(const bf16x8*)(xl_p + off);
    }
    bar_lds();                                        // bar2: xq reusable

    short* attq = xql;                                // [4 strips][16][64] bf16
    float* wtile = (float*)xqh;                       // [48][64] f32 (12 KB)
    {   // zero this wave's attq strip (pad rows s>=48 must read 0)
        bf16x8 z = {0, 0, 0, 0, 0, 0, 0, 0};
        *(bf16x8*)(attq + w * 1024 + l * 16) = z;
        *(bf16x8*)(attq + w * 1024 + l * 16 + 8) = z;
    }

    const int q = q0 + qrow;

    // ======== phase B: logits L[s][q] = srcT^T x (hi/lo split) ========
    const short* stBb = stB + (size_t)b * 12288;
    f32x4 accB[3];
    #pragma unroll
    for (int Mt = 0; Mt < 3; ++Mt) {
        f32x4 a = {0.f, 0.f, 0.f, 0.f};
        #pragma unroll
        for (int ks = 0; ks < 4; ++ks) {
            const bf16x8 sh = *(const bf16x8*)(stBb + ((((Mt * 4 + ks) * 2 + 0) * 64 + l) * 8));
            const bf16x8 sl = *(const bf16x8*)(stBb + ((((Mt * 4 + ks) * 2 + 1) * 64 + l) * 8));
            a = __builtin_amdgcn_mfma_f32_16x16x32_bf16(sh, fxh[ks], a, 0, 0, 0);
            a = __builtin_amdgcn_mfma_f32_16x16x32_bf16(sh, fxl[ks], a, 0, 0, 0);
            a = __builtin_amdgcn_mfma_f32_16x16x32_bf16(sl, fxh[ks], a, 0, 0, 0);
        }
        accB[Mt] = a;
    }

    // softmax over s per q (bias from L2-hot global array, f32x4 aligned)
    float mx = -INFINITY;
    #pragma unroll
    for (int Mt = 0; Mt < 3; ++Mt) {
        const f32x4 bias4 = *(const f32x4*)(biasB + b * SL + 16 * Mt + 4 * g);
        #pragma unroll
        for (int r = 0; r < 4; ++r) {
            float lv = accB[Mt][r] + bias4[r];
            accB[Mt][r] = lv;
            mx = fmaxf(mx, lv);
        }
    }
    mx = fmaxf(mx, __shfl_xor(mx, 16));
    mx = fmaxf(mx, __shfl_xor(mx, 32));
    float sum = 0.f;
    #pragma unroll
    for (int Mt = 0; Mt < 3; ++Mt)
        #pragma unroll
        for (int r = 0; r < 4; ++r) {
            float e = __expf(accB[Mt][r] - mx);
            accB[Mt][r] = e;
            sum += e;
        }
    sum += __shfl_xor(sum, 16);
    sum += __shfl_xor(sum, 32);
    float inv = 1.f / sum;
    #pragma unroll
    for (int Mt = 0; Mt < 3; ++Mt) {
        bf16x4 pv;
        #pragma unroll
        for (int r = 0; r < 4; ++r) {
            int s = 16 * Mt + 4 * g + r;
            float p = accB[Mt][r] * inv;
            wtile[s * 64 + (qrow ^ (((s >> 2) & 3) << 4))] = p;  // swizzled
            pv[r] = f2bf(p);
        }
        int sbase = 16 * Mt + 4 * g;
        *(bf16x4*)(attq + w * 1024 + c * 64 + (sbase ^ ((c & 7) << 3))) = pv;
    }

    // ---- phase C B-frags (same-wave attq RAW) ----
    bf16x8 fat[2];
    #pragma unroll
    for (int ks = 0; ks < 2; ++ks)
        fat[ks] = *(const bf16x8*)(attq + w * 1024 + c * 64 +
                                   ((32 * ks + 8 * g) ^ ((c & 7) << 3)));

    // ======== phase A: sv = (w_sv*sent) @ x (hi only), softmax over o ========
    const short* wsb = wsvS + (size_t)b * 16384;
    f32x4 accA[8];
    #pragma unroll
    for (int Mt = 0; Mt < 8; ++Mt) accA[Mt] = (f32x4){0.f, 0.f, 0.f, 0.f};
    #pragma unroll
    for (int Mt = 0; Mt < 8; ++Mt) {
        #pragma unroll
        for (int ks = 0; ks < 4; ++ks) {
            const bf16x8 wf = *(const bf16x8*)(wsb + (((Mt * 4 + ks) * 64 + l) * 8));
            accA[Mt] = __builtin_amdgcn_mfma_f32_16x16x32_bf16(wf, fxh[ks], accA[Mt], 0, 0, 0);
        }
    }
    float mA = -INFINITY;
    #pragma unroll
    for (int Mt = 0; Mt < 8; ++Mt)
        #pragma unroll
        for (int r = 0; r < 4; ++r) mA = fmaxf(mA, accA[Mt][r]);
    mA = fmaxf(mA, __shfl_xor(mA, 16));
    mA = fmaxf(mA, __shfl_xor(mA, 32));
    float sA = 0.f;
    #pragma unroll
    for (int Mt = 0; Mt < 8; ++Mt)
        #pragma unroll
        for (int r = 0; r < 4; ++r) {
            float e = __expf(accA[Mt][r] - mA);
            accA[Mt][r] = e;
            sA += e;
        }
    sA += __shfl_xor(sA, 16);
    sA += __shfl_xor(sA, 32);
    float invA = 1.f / sA;

    bar_lds();                                // bar3: wtile/attq writes done

    // coop store wattn (3 f32x4/thread; read-XOR = write-XOR >> 2)
    #pragma unroll
    for (int k = 0; k < 3; ++k) {
        int idx = k * 256 + t;                // 0..767
        int s = idx >> 4, q4 = idx & 15;
        f32x4 v = ((const f32x4*)wtile)[s * 16 + (q4 ^ (((s >> 2) & 3) << 2))];
        __builtin_nontemporal_store(v, (f32x4*)(wattn + ((size_t)b * SL + s) * QQ + q0 + q4 * 4));
    }
    bar_lds();                                // bar4: wtile reads done; xq dead

    float* tile = (float*)xq;                 // [128 o][64 q] f32, 32 KB
    #pragma unroll
    for (int Mt = 0; Mt < 8; ++Mt)
        #pragma unroll
        for (int r = 0; r < 4; ++r) {
            int o = 16 * Mt + 4 * g + r;
            tile[o * 64 + (qrow ^ (((o >> 2) & 3) << 4))] = accA[Mt][r] * invA;
        }
    bar_lds();                                // bar5: tile ready

    // coop store satt + wsent (sent from L2-hot global)
    #pragma unroll
    for (int k = 0; k < 8; ++k) {
        int idx = k * 256 + t;                // 0..2047
        int o = idx >> 4, q4 = idx & 15;
        f32x4 v = ((const f32x4*)tile)[o * 16 + (q4 ^ (((o >> 2) & 3) << 2))];
        size_t base = ((size_t)b * IDF + o) * QQ + q0 + q4 * 4;
        __builtin_nontemporal_store(v, (f32x4*)(satt + base));
        f32x4 vs = v * sentW[b * IDF + o];
        __builtin_nontemporal_store(vs, (f32x4*)(wsent + base));
    }

    // ======== phase C: wctx = srcT @ attn (overlaps store drain) ========
    const short* stCb = stC + (size_t)b * 8192;
    f32x4 accC[8];
    #pragma unroll
    for (int Mt = 0; Mt < 8; ++Mt) {
        f32x4 a = {0.f, 0.f, 0.f, 0.f};
        #pragma unroll
        for (int ks = 0; ks < 2; ++ks) {
            const bf16x8 cf = *(const bf16x8*)(stCb + (((Mt * 2 + ks) * 64 + l) * 8));
            a = __builtin_amdgcn_mfma_f32_16x16x32_bf16(cf, fat[ks], a, 0, 0, 0);
        }
        accC[Mt] = a;
    }
    bar_lds();                                // bar6: all tile reads done

    #pragma unroll
    for (int Mt = 0; Mt < 8; ++Mt)
        #pragma unroll
        for (int r = 0; r < 4; ++r) {
            int o = 16 * Mt + 4 * g + r;
            tile[o * 64 + (qrow ^ (((o >> 2) & 3) << 4))] = accC[Mt][r];
        }
    bar_lds();                                // bar7: tile ready

    #pragma unroll
    for (int k = 0; k < 8; ++k) {
        int idx = k * 256 + t;
        int o = idx >> 4, q4 = idx & 15;
        f32x4 v = ((const f32x4*)tile)[o * 16 + (q4 ^ (((o >> 2) & 3) << 2))];
        __builtin_nontemporal_store(v, (f32x4*)(wctx + ((size_t)b * IDF + o) * QQ + q0 + q4 * 4));
    }
}

extern "C" void kernel_launch(void* const* d_in, const int* in_sizes, int n_in,
                              void* d_out, int out_size, void* d_ws, size_t ws_size,
                              hipStream_t stream) {
    const float* input    = (const float*)d_in[0];
    const float* sentence = (const float*)d_in[1];
    const float* context  = (const float*)d_in[2];
    const int*   mask     = (const int*)d_in[3];
    const float* w_ctx    = (const float*)d_in[4];
    const float* w_sv     = (const float*)d_in[5];
    const float* w_lin    = (const float*)d_in[6];
    const float* b_lin    = (const float*)d_in[7];

    float* out = (float*)d_out;
    float* out_wctx  = out;
    float* out_wsent = out + (size_t)BB * IDF * QQ;
    float* out_wattn = out + 2 * (size_t)BB * IDF * QQ;
    float* out_satt  = out_wattn + (size_t)BB * SL * QQ;

    float* ws    = (float*)d_ws;
    float* sentW = ws;                       // 2048 f
    float* biasB = ws + 2048;                // 768 f
    short* wsvS  = (short*)(ws + 2816);      // 262144 h
    short* stB   = wsvS + 262144;            // 196608 h
    short* stC   = stB + 196608;             // 131072 h

    prepM_kernel<<<dim3(16), 256, 0, stream>>>(context, w_ctx, sentence,
                                               w_lin, b_lin, w_sv, mask,
                                               sentW, biasB, wsvS, stB, stC);
    fused_kernel<<<dim3(4096), 256, 0, stream>>>(input, stB, stC, wsvS,
                                                 sentW, biasB,
                                                 out_wctx, out_wsent,
                                                 out_wattn, out_satt);
}

// Round 18
// 120.403 us; speedup vs baseline: 1.1492x; 1.1492x over previous
//
#include <hip/hip_runtime.h>
#include <math.h>
#include <stdint.h>

#define BB  16
#define IDF 128
#define CDF 256
#define SL  48
#define QQ  16384   // 128*128
#define QT  64      // q-tile per block

typedef short bf16x8 __attribute__((ext_vector_type(8)));
typedef short bf16x4 __attribute__((ext_vector_type(4)));
typedef float f32x4  __attribute__((ext_vector_type(4)));

__device__ __forceinline__ short f2bf(float f) {      // RNE
    uint32_t u = __builtin_bit_cast(uint32_t, f);
    u += 0x7FFFu + ((u >> 16) & 1u);
    return (short)(u >> 16);
}
__device__ __forceinline__ short f2bf_t(float f) {    // truncate (for lo terms)
    return (short)(__builtin_bit_cast(uint32_t, f) >> 16);
}
__device__ __forceinline__ float bf2f(short h) {
    uint32_t u = ((uint32_t)(unsigned short)h) << 16;
    return __builtin_bit_cast(float, u);
}

// Barrier that orders LDS only (lgkmcnt) and lets global NT stores stay in
// flight (r16: -6 µs vs full __syncthreads drains).
__device__ __forceinline__ void bar_lds() {
    __builtin_amdgcn_sched_barrier(0);
    asm volatile("s_waitcnt lgkmcnt(0)" ::: "memory");
    __builtin_amdgcn_s_barrier();
    __builtin_amdgcn_sched_barrier(0);
}

// ============ prepM: srcT via MFMA + direct frag-array emission ============
__global__ __launch_bounds__(256) void prepM_kernel(
    const float* __restrict__ context,   // [B][CDF][SL]
    const float* __restrict__ w_ctx,     // [IDF][CDF]
    const float* __restrict__ sentence,  // [B][100]
    const float* __restrict__ w_lin,     // [IDF][100]
    const float* __restrict__ b_lin,     // [IDF]
    const float* __restrict__ w_sv,      // [IDF o][IDF i]
    const int*   __restrict__ mask,      // [B][SL]
    float* __restrict__ sentW,           // [B][IDF]
    float* __restrict__ biasB,           // [B][SL]
    short* __restrict__ wsvS,            // [B][8Mt][4ks][64][8]
    short* __restrict__ stB,             // [B][3Mt][4ks][2][64][8]
    short* __restrict__ stC)             // [B][8Mt][2ks][64][8]
{
    const int b = blockIdx.x;
    const int t = threadIdx.x;
    const int wv = t >> 6, l = t & 63;
    const int c = l & 15, g = l >> 4;

    __shared__ __align__(16) short ctxT_h[SL * CDF];   // 24 KB [s][c^swz] hi
    __shared__ __align__(16) short ctxT_l[SL * CDF];   // 24 KB lo
    __shared__ float srcTile[IDF * SL];                // 24 KB [i][s]
    __shared__ float sent_sh[IDF];

    if (t < IDF) {
        float a = b_lin[t];
        for (int k = 0; k < 100; ++k)
            a += sentence[b * 100 + k] * w_lin[t * 100 + k];
        sent_sh[t] = a;
        sentW[b * IDF + t] = a;
    }
    if (t >= IDF && t < IDF + SL) {
        int s = t - IDF;
        biasB[b * SL + s] = mask[b * SL + s] ? -INFINITY : 0.f;
    }

    for (int r = 0; r < 6; ++r) {
        int task = r * 256 + t;
        int cp = task & 127, s4 = task >> 7;
        int cd = cp * 2, sb = s4 * 4;
        const float* row0 = context + ((size_t)b * CDF + cd) * SL + sb;
        const float4 va = *(const float4*)(row0);
        const float4 vb = *(const float4*)(row0 + SL);
        float va_[4] = {va.x, va.y, va.z, va.w};
        float vb_[4] = {vb.x, vb.y, vb.z, vb.w};
        #pragma unroll
        for (int j = 0; j < 4; ++j) {
            int s = sb + j;
            short h0 = f2bf(va_[j]), h1 = f2bf(vb_[j]);
            short l0 = f2bf_t(va_[j] - bf2f(h0)), l1 = f2bf_t(vb_[j] - bf2f(h1));
            int e = s * CDF + (cd ^ ((s & 15) << 3));
            *(uint32_t*)(ctxT_h + e) = (uint32_t)(uint16_t)h0 | ((uint32_t)(uint16_t)h1 << 16);
            *(uint32_t*)(ctxT_l + e) = (uint32_t)(uint16_t)l0 | ((uint32_t)(uint16_t)l1 << 16);
        }
    }
    __syncthreads();

    #pragma unroll
    for (int mi = 0; mi < 2; ++mi) {
        const int Mt = wv * 2 + mi;
        const int m = 16 * Mt + c;
        bf16x8 Ah[8], Al[8];
        #pragma unroll
        for (int ks = 0; ks < 8; ++ks) {
            const float* wp = w_ctx + m * CDF + 8 * g + 32 * ks;
            const float4 f0 = *(const float4*)(wp);
            const float4 f1 = *(const float4*)(wp + 4);
            float fv[8] = {f0.x, f0.y, f0.z, f0.w, f1.x, f1.y, f1.z, f1.w};
            #pragma unroll
            for (int j = 0; j < 8; ++j) {
                short h = f2bf(fv[j]);
                Ah[ks][j] = h;
                Al[ks][j] = f2bf_t(fv[j] - bf2f(h));
            }
        }
        #pragma unroll
        for (int Nt = 0; Nt < 3; ++Nt) {
            const int s = 16 * Nt + c;
            f32x4 acc = {0.f, 0.f, 0.f, 0.f};
            #pragma unroll
            for (int ks = 0; ks < 8; ++ks) {
                int e = s * CDF + ((8 * g + 32 * ks) ^ ((s & 15) << 3));
                const bf16x8 Bh = *(const bf16x8*)(ctxT_h + e);
                const bf16x8 Bl = *(const bf16x8*)(ctxT_l + e);
                acc = __builtin_amdgcn_mfma_f32_16x16x32_bf16(Ah[ks], Bh, acc, 0, 0, 0);
                acc = __builtin_amdgcn_mfma_f32_16x16x32_bf16(Ah[ks], Bl, acc, 0, 0, 0);
                acc = __builtin_amdgcn_mfma_f32_16x16x32_bf16(Al[ks], Bh, acc, 0, 0, 0);
            }
            #pragma unroll
            for (int r = 0; r < 4; ++r)
                srcTile[(16 * Mt + 4 * g + r) * SL + s] = acc[r];
        }
    }
    __syncthreads();

    #pragma unroll
    for (int cc = 0; cc < 3; ++cc) {
        int comb = wv * 3 + cc;
        int Mt = comb >> 2, ks = comb & 3;
        int s = c + 16 * Mt;
        int ib = 8 * g + 32 * ks;
        bf16x8 hv, lv;
        #pragma unroll
        for (int j = 0; j < 8; ++j) {
            float v = srcTile[(ib + j) * SL + s];
            short h = f2bf(v);
            hv[j] = h;
            lv[j] = f2bf_t(v - bf2f(h));
        }
        size_t base = (size_t)b * 12288 + (((Mt * 4 + ks) * 2) * 64 + l) * 8;
        *(bf16x8*)(stB + base) = hv;
        *(bf16x8*)(stB + base + 512) = lv;
    }
    #pragma unroll
    for (int cc = 0; cc < 4; ++cc) {
        int comb = wv * 4 + cc;
        int Mt = comb >> 1, ks = comb & 1;
        int i = c + 16 * Mt;
        int sb = 8 * g + 32 * ks;
        bf16x8 v8;
        #pragma unroll
        for (int j = 0; j < 8; ++j) {
            int s = sb + j;
            v8[j] = (s < SL) ? f2bf(srcTile[i * SL + s]) : (short)0;
        }
        *(bf16x8*)(stC + (size_t)b * 8192 + ((Mt * 2 + ks) * 64 + l) * 8) = v8;
    }
    #pragma unroll
    for (int cc = 0; cc < 8; ++cc) {
        int comb = wv * 8 + cc;
        int Mt = comb >> 2, ks = comb & 3;
        int o = c + 16 * Mt;
        int ib = g * 8 + 32 * ks;
        bf16x8 outv;
        #pragma unroll
        for (int j = 0; j < 8; ++j)
            outv[j] = f2bf(w_sv[o * IDF + ib + j] * sent_sh[ib + j]);
        *(bf16x8*)(wsvS + (size_t)b * 16384 + ((Mt * 4 + ks) * 64 + l) * 8) = outv;
    }
}

// ===================== fused MFMA kernel =====================
// r16 optimum: NT stores + cached input loads + lgkm-only barriers +
// 4 blocks/CU + all outputs through swizzled LDS bounce tiles.
__global__ __launch_bounds__(256, 4) void fused_kernel(
    const float* __restrict__ input,   // [B][IDF][Q]
    const short* __restrict__ stB,
    const short* __restrict__ stC,
    const short* __restrict__ wsvS,
    const float* __restrict__ sentW,   // [B][IDF]
    const float* __restrict__ biasB,   // [B][SL]
    float* __restrict__ wctx, float* __restrict__ wsent,
    float* __restrict__ wattn, float* __restrict__ satt)
{
    const int bid = blockIdx.x;           // 4096 = 16 b x 256 tiles
    const int b   = bid >> 8;
    const int q0  = (bid & 255) * QT;
    const int t   = threadIdx.x;
    const int w   = t >> 6;               // wave -> q-strip (16 q)
    const int l   = t & 63;
    const int c   = l & 15;
    const int g   = l >> 4;

    __shared__ __align__(16) short xq[2 * QT * IDF];  // 32768 B

    short* xqh = xq;                      // 16 KB
    short* xql = xq + QT * IDF;           // 16 KB

    // ---- stage x transposed, hi/lo split ----
    {
        const int qb = (t & 15) * 4;
        #pragma unroll
        for (int r = 0; r < 4; ++r) {
            int i = (r * 16 + (t >> 4)) * 2;
            const float4 va = *(const float4*)(input + ((size_t)b * IDF + i    ) * QQ + q0 + qb);
            const float4 vb = *(const float4*)(input + ((size_t)b * IDF + i + 1) * QQ + q0 + qb);
            float va_[4] = {va.x, va.y, va.z, va.w};
            float vb_[4] = {vb.x, vb.y, vb.z, vb.w};
            #pragma unroll
            for (int jj = 0; jj < 4; ++jj) {
                int q = qb + jj;
                short h0 = f2bf(va_[jj]);
                short h1 = f2bf(vb_[jj]);
                short l0 = f2bf_t(va_[jj] - bf2f(h0));
                short l1 = f2bf_t(vb_[jj] - bf2f(h1));
                int e = q * IDF + (i ^ ((q & 15) << 3));   // i even -> e even
                *(uint32_t*)(xqh + e) = (uint32_t)(uint16_t)h0 | ((uint32_t)(uint16_t)h1 << 16);
                *(uint32_t*)(xql + e) = (uint32_t)(uint16_t)l0 | ((uint32_t)(uint16_t)l1 << 16);
            }
        }
    }
    bar_lds();                                        // bar1

    // ---- x B-fragments: plain b128, k = 32*ks + 8*g + j, n(q-col) = c ----
    const int qrow = 16 * w + c;
    const short* xh_p = xqh + qrow * IDF;
    const short* xl_p = xql + qrow * IDF;
    bf16x8 fxh[4], fxl[4];
    #pragma unroll
    for (int ks = 0; ks < 4; ++ks) {
        int off = (32 * ks + 8 * g) ^ (c << 3);       // qrow&15 == c
        fxh[ks] = *(const bf16x8*)(xh_p + off);
        fxl[ks] = *(const bf16x8*)(xl_p + off);
    }
    bar_lds();                                        // bar2: xq reusable

    short* attq = xql;                                // [4 strips][16][64] bf16
    float* wtile = (float*)xqh;                       // [48][64] f32 (12 KB)
    {   // zero this wave's attq strip (pad rows s>=48 must read 0)
        bf16x8 z = {0, 0, 0, 0, 0, 0, 0, 0};
        *(bf16x8*)(attq + w * 1024 + l * 16) = z;
        *(bf16x8*)(attq + w * 1024 + l * 16 + 8) = z;
    }

    const int q = q0 + qrow;

    // ======== phase B: logits L[s][q] = srcT^T x (hi/lo split) ========
    const short* stBb = stB + (size_t)b * 12288;
    f32x4 accB[3];
    #pragma unroll
    for (int Mt = 0; Mt < 3; ++Mt) {
        f32x4 a = {0.f, 0.f, 0.f, 0.f};
        #pragma unroll
        for (int ks = 0; ks < 4; ++ks) {
            const bf16x8 sh = *(const bf16x8*)(stBb + ((((Mt * 4 + ks) * 2 + 0) * 64 + l) * 8));
            const bf16x8 sl = *(const bf16x8*)(stBb + ((((Mt * 4 + ks) * 2 + 1) * 64 + l) * 8));
            a = __builtin_amdgcn_mfma_f32_16x16x32_bf16(sh, fxh[ks], a, 0, 0, 0);
            a = __builtin_amdgcn_mfma_f32_16x16x32_bf16(sh, fxl[ks], a, 0, 0, 0);
            a = __builtin_amdgcn_mfma_f32_16x16x32_bf16(sl, fxh[ks], a, 0, 0, 0);
        }
        accB[Mt] = a;
    }

    // softmax over s per q (bias from L2-hot global array, f32x4 aligned)
    float mx = -INFINITY;
    #pragma unroll
    for (int Mt = 0; Mt < 3; ++Mt) {
        const f32x4 bias4 = *(const f32x4*)(biasB + b * SL + 16 * Mt + 4 * g);
        #pragma unroll
        for (int r = 0; r < 4; ++r) {
            float lv = accB[Mt][r] + bias4[r];
            accB[Mt][r] = lv;
            mx = fmaxf(mx, lv);
        }
    }
    mx = fmaxf(mx, __shfl_xor(mx, 16));
    mx = fmaxf(mx, __shfl_xor(mx, 32));
    float sum = 0.f;
    #pragma unroll
    for (int Mt = 0; Mt < 3; ++Mt)
        #pragma unroll
        for (int r = 0; r < 4; ++r) {
            float e = __expf(accB[Mt][r] - mx);
            accB[Mt][r] = e;
            sum += e;
        }
    sum += __shfl_xor(sum, 16);
    sum += __shfl_xor(sum, 32);
    float inv = 1.f / sum;
    #pragma unroll
    for (int Mt = 0; Mt < 3; ++Mt) {
        bf16x4 pv;
        #pragma unroll
        for (int r = 0; r < 4; ++r) {
            int s = 16 * Mt + 4 * g + r;
            float p = accB[Mt][r] * inv;
            wtile[s * 64 + (qrow ^ (((s >> 2) & 3) << 4))] = p;  // swizzled
            pv[r] = f2bf(p);
        }
        int sbase = 16 * Mt + 4 * g;
        *(bf16x4*)(attq + w * 1024 + c * 64 + (sbase ^ ((c & 7) << 3))) = pv;
    }

    // ---- phase C B-frags (same-wave attq RAW) ----
    bf16x8 fat[2];
    #pragma unroll
    for (int ks = 0; ks < 2; ++ks)
        fat[ks] = *(const bf16x8*)(attq + w * 1024 + c * 64 +
                                   ((32 * ks + 8 * g) ^ ((c & 7) << 3)));

    // ======== phase A: sv = (w_sv*sent) @ x (hi only), softmax over o ========
    const short* wsb = wsvS + (size_t)b * 16384;
    f32x4 accA[8];
    #pragma unroll
    for (int Mt = 0; Mt < 8; ++Mt) accA[Mt] = (f32x4){0.f, 0.f, 0.f, 0.f};
    #pragma unroll
    for (int Mt = 0; Mt < 8; ++Mt) {
        #pragma unroll
        for (int ks = 0; ks < 4; ++ks) {
            const bf16x8 wf = *(const bf16x8*)(wsb + (((Mt * 4 + ks) * 64 + l) * 8));
            accA[Mt] = __builtin_amdgcn_mfma_f32_16x16x32_bf16(wf, fxh[ks], accA[Mt], 0, 0, 0);
        }
    }
    float mA = -INFINITY;
    #pragma unroll
    for (int Mt = 0; Mt < 8; ++Mt)
        #pragma unroll
        for (int r = 0; r < 4; ++r) mA = fmaxf(mA, accA[Mt][r]);
    mA = fmaxf(mA, __shfl_xor(mA, 16));
    mA = fmaxf(mA, __shfl_xor(mA, 32));
    float sA = 0.f;
    #pragma unroll
    for (int Mt = 0; Mt < 8; ++Mt)
        #pragma unroll
        for (int r = 0; r < 4; ++r) {
            float e = __expf(accA[Mt][r] - mA);
            accA[Mt][r] = e;
            sA += e;
        }
    sA += __shfl_xor(sA, 16);
    sA += __shfl_xor(sA, 32);
    float invA = 1.f / sA;

    bar_lds();                                // bar3: wtile/attq writes done

    // coop store wattn (3 f32x4/thread; read-XOR = write-XOR >> 2)
    #pragma unroll
    for (int k = 0; k < 3; ++k) {
        int idx = k * 256 + t;                // 0..767
        int s = idx >> 4, q4 = idx & 15;
        f32x4 v = ((const f32x4*)wtile)[s * 16 + (q4 ^ (((s >> 2) & 3) << 2))];
        __builtin_nontemporal_store(v, (f32x4*)(wattn + ((size_t)b * SL + s) * QQ + q0 + q4 * 4));
    }
    bar_lds();                                // bar4: wtile reads done; xq dead

    float* tile = (float*)xq;                 // [128 o][64 q] f32, 32 KB
    #pragma unroll
    for (int Mt = 0; Mt < 8; ++Mt)
        #pragma unroll
        for (int r = 0; r < 4; ++r) {
            int o = 16 * Mt + 4 * g + r;
            tile[o * 64 + (qrow ^ (((o >> 2) & 3) << 4))] = accA[Mt][r] * invA;
        }
    bar_lds();                                // bar5: tile ready

    // coop store satt + wsent (sent from L2-hot global)
    #pragma unroll
    for (int k = 0; k < 8; ++k) {
        int idx = k * 256 + t;                // 0..2047
        int o = idx >> 4, q4 = idx & 15;
        f32x4 v = ((const f32x4*)tile)[o * 16 + (q4 ^ (((o >> 2) & 3) << 2))];
        size_t base = ((size_t)b * IDF + o) * QQ + q0 + q4 * 4;
        __builtin_nontemporal_store(v, (f32x4*)(satt + base));
        f32x4 vs = v * sentW[b * IDF + o];
        __builtin_nontemporal_store(vs, (f32x4*)(wsent + base));
    }

    // ======== phase C: wctx = srcT @ attn (overlaps store drain) ========
    const short* stCb = stC + (size_t)b * 8192;
    f32x4 accC[8];
    #pragma unroll
    for (int Mt = 0; Mt < 8; ++Mt) {
        f32x4 a = {0.f, 0.f, 0.f, 0.f};
        #pragma unroll
        for (int ks = 0; ks < 2; ++ks) {
            const bf16x8 cf = *(const bf16x8*)(stCb + (((Mt * 2 + ks) * 64 + l) * 8));
            a = __builtin_amdgcn_mfma_f32_16x16x32_bf16(cf, fat[ks], a, 0, 0, 0);
        }
        accC[Mt] = a;
    }
    bar_lds();                                // bar6: all tile reads done

    #pragma unroll
    for (int Mt = 0; Mt < 8; ++Mt)
        #pragma unroll
        for (int r = 0; r < 4; ++r) {
            int o = 16 * Mt + 4 * g + r;
            tile[o * 64 + (qrow ^ (((o >> 2) & 3) << 4))] = accC[Mt][r];
        }
    bar_lds();                                // bar7: tile ready

    #pragma unroll
    for (int k = 0; k < 8; ++k) {
        int idx = k * 256 + t;
        int o = idx >> 4, q4 = idx & 15;
        f32x4 v = ((const f32x4*)tile)[o * 16 + (q4 ^ (((o >> 2) & 3) << 2))];
        __builtin_nontemporal_store(v, (f32x4*)(wctx + ((size_t)b * IDF + o) * QQ + q0 + q4 * 4));
    }
}

extern "C" void kernel_launch(void* const* d_in, const int* in_sizes, int n_in,
                              void* d_out, int out_size, void* d_ws, size_t ws_size,
                              hipStream_t stream) {
    const float* input    = (const float*)d_in[0];
    const float* sentence = (const float*)d_in[1];
    const float* context  = (const float*)d_in[2];
    const int*   mask     = (const int*)d_in[3];
    const float* w_ctx    = (const float*)d_in[4];
    const float* w_sv     = (const float*)d_in[5];
    const float* w_lin    = (const float*)d_in[6];
    const float* b_lin    = (const float*)d_in[7];

    float* out = (float*)d_out;
    float* out_wctx  = out;
    float* out_wsent = out + (size_t)BB * IDF * QQ;
    float* out_wattn = out + 2 * (size_t)BB * IDF * QQ;
    float* out_satt  = out_wattn + (size_t)BB * SL * QQ;

    float* ws    = (float*)d_ws;
    float* sentW = ws;                       // 2048 f
    float* biasB = ws + 2048;                // 768 f
    short* wsvS  = (short*)(ws + 2816);      // 262144 h
    short* stB   = wsvS + 262144;            // 196608 h
    short* stC   = stB + 196608;             // 131072 h

    prepM_kernel<<<dim3(16), 256, 0, stream>>>(context, w_ctx, sentence,
                                               w_lin, b_lin, w_sv, mask,
                                               sentW, biasB, wsvS, stB, stC);
    fused_kernel<<<dim3(4096), 256, 0, stream>>>(input, stB, stC, wsvS,
                                                 sentW, biasB,
                                                 out_wctx, out_wsent,
                                                 out_wattn, out_satt);
}